// Round 1
// baseline (208.080 us; speedup 1.0000x reference)
//
#include <hip/hip_runtime.h>
#include <hip/hip_bf16.h>

// BiaffineAttention on MI355X.
// Pipeline (all GEMMs are bf16-MFMA "C = A @ B^T + bias" with A=500 padded to 512):
//  k_conv_hs : hs fp32 -> bf16                        [8192,1024]
//  k_w1      : W1cat = [w1h; w1d] -> bf16 (N pad 0)   [1024,1024], b1cat fp32[1024]
//  k_w2d     : w2d -> bf16 padded                     [512,512]
//  k_mt      : MT[a,k] = sum_j w2h[j,k]*Wb[j,a] bf16  [512,512]  (folds head@Wb)
//  k_bc      : bc[a] = sum_j b2h[j]*Wb[j,a]; b2d pad; bias_s[:]=bb
//  GEMM1: t1 = relu(hs @ W1cat^T + b1cat)             [8192,1024] bf16
//  GEMM2: z=0 headW = t1[:,0:512] @ MT^T  + bc        [8192,512] bf16
//         z=1 dep   = t1[:,512: ] @ w2d^T + b2d       [8192,512] bf16
//  GEMM3: scores[b] = headW_b @ dep_b^T + bb -> f32 d_out (z=16 batches)

#define HIDDEN 1024
#define ARC 500
#define AP 512
#define ROWS 8192

typedef __attribute__((ext_vector_type(4))) float f32x4;
typedef __attribute__((ext_vector_type(8))) short short8;

static __device__ __forceinline__ ushort f2bf(float f) {
  union { float f; unsigned u; } v; v.f = f;
  unsigned r = v.u + 0x7fffu + ((v.u >> 16) & 1u);  // RNE
  return (ushort)(r >> 16);
}

__global__ void k_conv_hs(const float4* __restrict__ in, ushort* __restrict__ out, int n4) {
  int i = blockIdx.x * blockDim.x + threadIdx.x;
  int st = gridDim.x * blockDim.x;
  for (; i < n4; i += st) {
    float4 v = in[i];
    ushort4 o;
    o.x = f2bf(v.x); o.y = f2bf(v.y); o.z = f2bf(v.z); o.w = f2bf(v.w);
    *(ushort4*)(out + (size_t)i * 4) = o;
  }
}

__global__ void k_w1(const float* __restrict__ w1h, const float* __restrict__ b1h,
                     const float* __restrict__ w1d, const float* __restrict__ b1d,
                     ushort* __restrict__ W1, float* __restrict__ b1) {
  int idx = blockIdx.x * 256 + threadIdx.x;  // 1024*1024 total
  int n = idx >> 10, k = idx & 1023;
  float v = 0.f;
  if (n < AP) { if (n < ARC) v = w1h[(size_t)n * HIDDEN + k]; }
  else        { int n2 = n - AP; if (n2 < ARC) v = w1d[(size_t)n2 * HIDDEN + k]; }
  W1[idx] = f2bf(v);
  if (idx < 1024) {
    float bv = 0.f;
    if (idx < AP) { if (idx < ARC) bv = b1h[idx]; }
    else          { if (idx - AP < ARC) bv = b1d[idx - AP]; }
    b1[idx] = bv;
  }
}

__global__ void k_w2d(const float* __restrict__ w2d, ushort* __restrict__ W2) {
  int idx = blockIdx.x * 256 + threadIdx.x;  // 512*512
  int n = idx >> 9, k = idx & 511;
  float v = (n < ARC && k < ARC) ? w2d[(size_t)n * ARC + k] : 0.f;
  W2[idx] = f2bf(v);
}

// MT[a,k] = sum_j w2h[j,k] * Wb[j,a]  (fp32 accumulate, bf16 out, padded to 512x512)
__global__ void k_mt(const float* __restrict__ w2h, const float* __restrict__ Wb,
                     ushort* __restrict__ MT) {
  int k = blockIdx.x * 256 + threadIdx.x;  // grid (2, 512)
  int a = blockIdx.y;
  float s = 0.f;
  if (a < ARC && k < ARC) {
    for (int j = 0; j < ARC; ++j) s += w2h[(size_t)j * ARC + k] * Wb[(size_t)j * ARC + a];
  }
  MT[(size_t)a * AP + k] = f2bf(s);
}

__global__ void k_bc(const float* __restrict__ b2h, const float* __restrict__ Wb,
                     const float* __restrict__ b2d, const float* __restrict__ bb,
                     float* __restrict__ bias2, float* __restrict__ biasS) {
  int a = threadIdx.x;  // 512
  float s = 0.f;
  if (a < ARC) {
    for (int j = 0; j < ARC; ++j) s += b2h[j] * Wb[(size_t)j * ARC + a];
  }
  bias2[a] = s;                               // bc (pad rows -> 0 since s=0)
  bias2[AP + a] = (a < ARC) ? b2d[a] : 0.f;   // b2d padded
  biasS[a] = bb[0];                           // scores bias broadcast
}

// ---- m97-structure bf16 GEMM: C = A @ B^T (+bias[n], opt ReLU) -------------
// 128x128 tile, BK=32, 256 threads (4 waves, 2x2), 16x16x32 bf16 MFMA,
// global_load_lds width-16 staging, 2-barrier K loop.
template <bool RELU, bool OUT_BF16>
__global__ __launch_bounds__(256)
void k_gemm_bt(const ushort* __restrict__ A, const ushort* __restrict__ B,
               const float* __restrict__ bias, void* __restrict__ Cv,
               int lda, int ldb, int ldc, int K,
               long aBS, long bBS, long cBS, long biasBS) {
  __shared__ ushort As[128 * 32];
  __shared__ ushort Bs[128 * 32];
  const int t = threadIdx.x;
  const int w = t >> 6;
  const int l = t & 63;
  const int z = blockIdx.z;
  A += (size_t)aBS * z;
  B += (size_t)bBS * z;
  bias += (size_t)biasBS * z;
  const int tm = blockIdx.x * 128;
  const int tn = blockIdx.y * 128;
  const int wr = w >> 1, wc = w & 1;

  f32x4 acc[4][4];
#pragma unroll
  for (int m = 0; m < 4; ++m)
#pragma unroll
    for (int n = 0; n < 4; ++n) acc[m][n] = f32x4{0.f, 0.f, 0.f, 0.f};

  // staging: per K-tile, A tile = 128x32 bf16 = 8 KB = 2 calls x (256 thr x 16B)
  const int srow = w * 16 + (l >> 2);      // + c*64
  const int scol = (l & 3) * 8;
  const ushort* ag = A + (size_t)(tm + srow) * lda + scol;
  const ushort* bg = B + (size_t)(tn + srow) * ldb + scol;
  ushort* lA = As + w * 512;               // wave-uniform LDS base (+ c*2048)
  ushort* lB = Bs + w * 512;

  const int fr = l & 15, fh = l >> 4;      // fragment row / k-half
  const ushort* fA = As + (size_t)(wr * 64 + fr) * 32 + fh * 8;
  const ushort* fB = Bs + (size_t)(wc * 64 + fr) * 32 + fh * 8;

  for (int kt = 0; kt < K; kt += 32) {
#pragma unroll
    for (int c = 0; c < 2; ++c) {
      __builtin_amdgcn_global_load_lds(
          (const __attribute__((address_space(1))) void*)(ag + (size_t)c * 64 * lda + kt),
          (__attribute__((address_space(3))) void*)(lA + c * 2048), 16, 0, 0);
      __builtin_amdgcn_global_load_lds(
          (const __attribute__((address_space(1))) void*)(bg + (size_t)c * 64 * ldb + kt),
          (__attribute__((address_space(3))) void*)(lB + c * 2048), 16, 0, 0);
    }
    asm volatile("s_waitcnt vmcnt(0)" ::: "memory");
    __syncthreads();

    short8 af[4], bf[4];
#pragma unroll
    for (int m = 0; m < 4; ++m) af[m] = *(const short8*)(fA + m * 16 * 32);
#pragma unroll
    for (int n = 0; n < 4; ++n) bf[n] = *(const short8*)(fB + n * 16 * 32);
#pragma unroll
    for (int m = 0; m < 4; ++m)
#pragma unroll
      for (int n = 0; n < 4; ++n)
        acc[m][n] = __builtin_amdgcn_mfma_f32_16x16x32_bf16(af[m], bf[n], acc[m][n], 0, 0, 0);
    __syncthreads();
  }

  // epilogue: C/D layout col = lane&15, row = (lane>>4)*4 + j  [m89-verified]
  const int cr = fh * 4;
  const int cc = fr;
#pragma unroll
  for (int m = 0; m < 4; ++m) {
#pragma unroll
    for (int n = 0; n < 4; ++n) {
      const int col = tn + wc * 64 + n * 16 + cc;
      const float bv = bias[col];
#pragma unroll
      for (int j = 0; j < 4; ++j) {
        const int row = tm + wr * 64 + m * 16 + cr + j;
        float v = acc[m][n][j] + bv;
        if (RELU) v = fmaxf(v, 0.f);
        if (OUT_BF16)
          ((ushort*)Cv)[(size_t)cBS * z + (size_t)row * ldc + col] = f2bf(v);
        else
          ((float*)Cv)[(size_t)cBS * z + (size_t)row * ldc + col] = v;
      }
    }
  }
}

extern "C" void kernel_launch(void* const* d_in, const int* in_sizes, int n_in,
                              void* d_out, int out_size, void* d_ws, size_t ws_size,
                              hipStream_t stream) {
  const float* hs  = (const float*)d_in[0];
  const float* w1h = (const float*)d_in[1];
  const float* b1h = (const float*)d_in[2];
  const float* w2h = (const float*)d_in[3];
  const float* b2h = (const float*)d_in[4];
  const float* w1d = (const float*)d_in[5];
  const float* b1d = (const float*)d_in[6];
  const float* w2d = (const float*)d_in[7];
  const float* b2d = (const float*)d_in[8];
  const float* Wb  = (const float*)d_in[9];
  const float* bb  = (const float*)d_in[10];

  char* ws = (char*)d_ws;
  ushort* hs_bf = (ushort*)(ws + 0);          // 16,777,216 B
  ushort* W1    = (ushort*)(ws + 16777216);   //  2,097,152
  ushort* MT    = (ushort*)(ws + 18874368);   //    524,288
  ushort* W2    = (ushort*)(ws + 19398656);   //    524,288 (must be MT+512*512 elems)
  ushort* t1    = (ushort*)(ws + 19922944);   // 16,777,216
  ushort* hw    = (ushort*)(ws + 36700160);   //  8,388,608 headW
  // dep = hw + 8192*512 elements            //  8,388,608
  float*  b1c   = (float*)(ws + 53477376);    //      4,096
  float*  b2c   = (float*)(ws + 53481472);    //      4,096 (bc | b2d)
  float*  bS    = (float*)(ws + 53485568);    //      2,048
  float*  out   = (float*)d_out;

  // --- prep ---
  k_conv_hs<<<2048, 256, 0, stream>>>((const float4*)hs, hs_bf, ROWS * HIDDEN / 4);
  k_w1<<<4096, 256, 0, stream>>>(w1h, b1h, w1d, b1d, W1, b1c);
  k_w2d<<<1024, 256, 0, stream>>>(w2d, W2);
  k_mt<<<dim3(2, 512), 256, 0, stream>>>(w2h, Wb, MT);
  k_bc<<<1, 512, 0, stream>>>(b2h, Wb, b2d, bb, b2c, bS);

  // --- GEMM1: t1 = relu(hs @ W1cat^T + b1cat)   [8192 x 1024], K=1024 ---
  k_gemm_bt<true, true><<<dim3(64, 8, 1), 256, 0, stream>>>(
      hs_bf, W1, b1c, t1, HIDDEN, HIDDEN, 1024, HIDDEN, 0, 0, 0, 0);

  // --- GEMM2: z=0 headW = t1[:,:512]@MT^T+bc ; z=1 dep = t1[:,512:]@W2^T+b2d ---
  k_gemm_bt<false, true><<<dim3(64, 4, 2), 256, 0, stream>>>(
      t1, MT, b2c, hw, 1024, AP, AP, AP,
      /*aBS=*/AP, /*bBS=*/(long)AP * AP, /*cBS=*/(long)ROWS * AP, /*biasBS=*/AP);

  // --- GEMM3: scores[b] = headW_b @ dep_b^T + bb  -> f32 d_out, 16 batches ---
  k_gemm_bt<false, false><<<dim3(4, 4, 16), 256, 0, stream>>>(
      hw, hw + (size_t)ROWS * AP, bS, out, AP, AP, 512, AP,
      /*aBS=*/(long)512 * AP, /*bBS=*/(long)512 * AP, /*cBS=*/(long)512 * 512,
      /*biasBS=*/0);
}

// Round 2
// 177.348 us; speedup vs baseline: 1.1733x; 1.1733x over previous
//
#include <hip/hip_runtime.h>
#include <hip/hip_bf16.h>

// BiaffineAttention on MI355X — round 2.
// All GEMMs: bf16 MFMA "C = A @ B^T" (m97 structure, 128xBN tile, BK=32).
// Algebraic folds:
//  MT = Wb^T @ w2h  (as GEMM: A=WbT, B=w2hT) with w2hT row 511 = b2h
//    -> MT[:,511] = bc = b2h @ Wb  (bias of headW folded into MT)
//  W2 column 511 = b2d (bias of dep folded)
//  b1c[511] = b1c[1023] = 1.0 so t1[:,511] = t1[:,1023] = 1 after ReLU
//  => GEMM2 needs no bias; GEMM3 adds scalar bb[0].
// Pipeline: k_conv_hs; k_prep; GEMM_MT(512^3); GEMM1(relu, 8192x1024,K=1024);
//           GEMM2(z=2: headW|dep, 8192x512,K=512); GEMM3(z=16 batched, ->f32 out).

#define HIDDEN 1024
#define ARC 500
#define AP 512
#define ROWS 8192

typedef __attribute__((ext_vector_type(4))) float f32x4;
typedef __attribute__((ext_vector_type(8))) short short8;

static __device__ __forceinline__ ushort f2bf(float f) {
  union { float f; unsigned u; } v; v.f = f;
  unsigned r = v.u + 0x7fffu + ((v.u >> 16) & 1u);  // RNE
  return (ushort)(r >> 16);
}

__global__ void k_conv_hs(const float4* __restrict__ in, ushort* __restrict__ out, int n4) {
  int i = blockIdx.x * blockDim.x + threadIdx.x;
  int st = gridDim.x * blockDim.x;
  for (; i < n4; i += st) {
    float4 v = in[i];
    ushort4 o;
    o.x = f2bf(v.x); o.y = f2bf(v.y); o.z = f2bf(v.z); o.w = f2bf(v.w);
    *(ushort4*)(out + (size_t)i * 4) = o;
  }
}

// One fused weight-prep kernel. Block ranges:
//  [0,4096)    W1 [1024x1024]: rows 0..499=w1h, 512..1011=w1d, else 0
//  [4096,5120) WbT [512x512]: WbT[a][j] = Wb[j][a]
//  [5120,6144) w2hT [512x512]: w2hT[k][j] = w2h[j][k]; row 511 = b2h
//  [6144,7168) W2 [512x512]: w2d padded; col 511 = b2d
//  [7168,7172) b1c [1024] f32: b1h | pad | 1 | b1d | pad | 1
__global__ void k_prep(const float* __restrict__ w1h, const float* __restrict__ b1h,
                       const float* __restrict__ w1d, const float* __restrict__ b1d,
                       const float* __restrict__ w2h, const float* __restrict__ b2h,
                       const float* __restrict__ w2d, const float* __restrict__ b2d,
                       const float* __restrict__ Wb,
                       ushort* __restrict__ W1, ushort* __restrict__ WbT,
                       ushort* __restrict__ w2hT, ushort* __restrict__ W2,
                       float* __restrict__ b1c) {
  const int bid = blockIdx.x;
  const int tid = threadIdx.x;
  if (bid < 4096) {
    int idx = bid * 256 + tid;
    int n = idx >> 10, k = idx & 1023;
    float v = 0.f;
    if (n < ARC) v = w1h[(size_t)n * HIDDEN + k];
    else if (n >= AP && n < AP + ARC) v = w1d[(size_t)(n - AP) * HIDDEN + k];
    W1[idx] = f2bf(v);
  } else if (bid < 5120) {
    int idx = (bid - 4096) * 256 + tid;
    int a = idx >> 9, j = idx & 511;
    float v = (a < ARC && j < ARC) ? Wb[(size_t)j * ARC + a] : 0.f;
    WbT[idx] = f2bf(v);
  } else if (bid < 6144) {
    int idx = (bid - 5120) * 256 + tid;
    int k = idx >> 9, j = idx & 511;
    float v = 0.f;
    if (j < ARC) {
      if (k < ARC) v = w2h[(size_t)j * ARC + k];
      else if (k == 511) v = b2h[j];
    }
    w2hT[idx] = f2bf(v);
  } else if (bid < 7168) {
    int idx = (bid - 6144) * 256 + tid;
    int n = idx >> 9, k = idx & 511;
    float v = 0.f;
    if (n < ARC) {
      if (k < ARC) v = w2d[(size_t)n * ARC + k];
      else if (k == 511) v = b2d[n];
    }
    W2[idx] = f2bf(v);
  } else {
    int i = (bid - 7168) * 256 + tid;  // [0,1024)
    float v = 0.f;
    if (i < ARC) v = b1h[i];
    else if (i == 511 || i == 1023) v = 1.f;
    else if (i >= AP && i < AP + ARC) v = b1d[i - AP];
    b1c[i] = v;
  }
}

// ---- bf16 GEMM: C = A @ B^T (+bias, opt ReLU) ------------------------------
// 128xBN tile, BK=32, 256 threads (4 waves), 16x16x32 bf16 MFMA,
// global_load_lds width-16 staging, 2-barrier K loop, XCD-bijective swizzle.
// BIAS_MODE: 0 = none, 1 = per-col vector, 2 = scalar bias[0].
template <bool RELU, bool OUT_BF16, int BIAS_MODE, int BN>
__global__ __launch_bounds__(256)
void k_gemm_bt(const ushort* __restrict__ A, const ushort* __restrict__ B,
               const float* __restrict__ bias, void* __restrict__ Cv,
               int lda, int ldb, int ldc, int K,
               long aBS, long bBS, long cBS) {
  constexpr int WC = BN / 2;    // per-wave col span
  constexpr int NFR = WC / 16;  // n-fragments per wave (4 or 2)
  __shared__ ushort As[128 * 32];
  __shared__ ushort Bs[BN * 32];

  // XCD-bijective swizzle (all grids have nwg % 8 == 0)
  const int gx = gridDim.x, gy = gridDim.y;
  const int gxy = gx * gy;
  const int nwg = gxy * gridDim.z;
  const int flat = (blockIdx.z * gy + blockIdx.y) * gx + blockIdx.x;
  const int q = nwg >> 3;
  const int f2 = (flat & 7) * q + (flat >> 3);
  const int bz = f2 / gxy;
  const int rm = f2 - bz * gxy;
  const int by = rm / gx;
  const int bx = rm - by * gx;

  const int t = threadIdx.x;
  const int w = t >> 6;
  const int l = t & 63;
  A += (size_t)aBS * bz;
  B += (size_t)bBS * bz;
  const int tm = by * 128;
  const int tn = bx * BN;
  const int wr = w >> 1, wc = w & 1;

  f32x4 acc[4][NFR];
#pragma unroll
  for (int m = 0; m < 4; ++m)
#pragma unroll
    for (int n = 0; n < NFR; ++n) acc[m][n] = f32x4{0.f, 0.f, 0.f, 0.f};

  const int srow = w * 16 + (l >> 2);
  const int scol = (l & 3) * 8;
  const ushort* ag = A + (size_t)(tm + srow) * lda + scol;
  const ushort* bg = B + (size_t)(tn + srow) * ldb + scol;
  ushort* lA = As + w * 512;
  ushort* lB = Bs + w * 512;

  const int fr = l & 15, fh = l >> 4;
  const ushort* fA = As + (size_t)(wr * 64 + fr) * 32 + fh * 8;
  const ushort* fB = Bs + (size_t)(wc * WC + fr) * 32 + fh * 8;

  for (int kt = 0; kt < K; kt += 32) {
#pragma unroll
    for (int c = 0; c < 2; ++c)
      __builtin_amdgcn_global_load_lds(
          (const __attribute__((address_space(1))) void*)(ag + (size_t)c * 64 * lda + kt),
          (__attribute__((address_space(3))) void*)(lA + c * 2048), 16, 0, 0);
#pragma unroll
    for (int c = 0; c < BN / 64; ++c)
      __builtin_amdgcn_global_load_lds(
          (const __attribute__((address_space(1))) void*)(bg + (size_t)c * 64 * ldb + kt),
          (__attribute__((address_space(3))) void*)(lB + c * 2048), 16, 0, 0);
    asm volatile("s_waitcnt vmcnt(0)" ::: "memory");
    __syncthreads();

    short8 af[4], bf[NFR];
#pragma unroll
    for (int m = 0; m < 4; ++m) af[m] = *(const short8*)(fA + m * 16 * 32);
#pragma unroll
    for (int n = 0; n < NFR; ++n) bf[n] = *(const short8*)(fB + n * 16 * 32);
#pragma unroll
    for (int m = 0; m < 4; ++m)
#pragma unroll
      for (int n = 0; n < NFR; ++n)
        acc[m][n] = __builtin_amdgcn_mfma_f32_16x16x32_bf16(af[m], bf[n], acc[m][n], 0, 0, 0);
    __syncthreads();
  }

  // C/D layout: col = lane&15, row = (lane>>4)*4 + j  [m89-verified]
  const int cr = fh * 4;
  const float bscal = (BIAS_MODE == 2) ? bias[0] : 0.f;
#pragma unroll
  for (int m = 0; m < 4; ++m) {
#pragma unroll
    for (int n = 0; n < NFR; ++n) {
      const int col = tn + wc * WC + n * 16 + fr;
      const float bv = (BIAS_MODE == 1) ? bias[col] : bscal;
#pragma unroll
      for (int j = 0; j < 4; ++j) {
        const int row = tm + wr * 64 + m * 16 + cr + j;
        float v = acc[m][n][j] + bv;
        if (RELU) v = fmaxf(v, 0.f);
        if (OUT_BF16)
          ((ushort*)Cv)[(size_t)cBS * bz + (size_t)row * ldc + col] = f2bf(v);
        else
          ((float*)Cv)[(size_t)cBS * bz + (size_t)row * ldc + col] = v;
      }
    }
  }
}

extern "C" void kernel_launch(void* const* d_in, const int* in_sizes, int n_in,
                              void* d_out, int out_size, void* d_ws, size_t ws_size,
                              hipStream_t stream) {
  const float* hs  = (const float*)d_in[0];
  const float* w1h = (const float*)d_in[1];
  const float* b1h = (const float*)d_in[2];
  const float* w2h = (const float*)d_in[3];
  const float* b2h = (const float*)d_in[4];
  const float* w1d = (const float*)d_in[5];
  const float* b1d = (const float*)d_in[6];
  const float* w2d = (const float*)d_in[7];
  const float* b2d = (const float*)d_in[8];
  const float* Wb  = (const float*)d_in[9];
  const float* bb  = (const float*)d_in[10];

  char* ws = (char*)d_ws;
  ushort* hs_bf = (ushort*)(ws + 0);          // 16 MB
  ushort* W1    = (ushort*)(ws + 16777216);   // 2 MB
  ushort* WbT   = (ushort*)(ws + 18874368);   // 512 KB
  ushort* w2hT  = (ushort*)(ws + 19398656);   // 512 KB
  ushort* MT    = (ushort*)(ws + 19922944);   // 512 KB
  ushort* W2    = (ushort*)(ws + 20447232);   // 512 KB  (= MT + 512*512 elems!)
  ushort* t1    = (ushort*)(ws + 20971520);   // 16 MB
  ushort* hw    = (ushort*)(ws + 37748736);   // 16 MB (headW 8MB | dep 8MB)
  float*  b1c   = (float*)(ws + 54525952);    // 4 KB
  float*  out   = (float*)d_out;

  k_conv_hs<<<2048, 256, 0, stream>>>((const float4*)hs, hs_bf, ROWS * HIDDEN / 4);
  k_prep<<<7172, 256, 0, stream>>>(w1h, b1h, w1d, b1d, w2h, b2h, w2d, b2d, Wb,
                                   W1, WbT, w2hT, W2, b1c);

  // MT = WbT @ w2hT^T  [512x512], K=512 (MT[:,511] = bc)
  k_gemm_bt<false, true, 0, 128><<<dim3(4, 4, 1), 256, 0, stream>>>(
      WbT, w2hT, nullptr, MT, AP, AP, AP, AP, 0, 0, 0);

  // GEMM1: t1 = relu(hs @ W1^T + b1c)  [8192 x 1024], K=1024
  k_gemm_bt<true, true, 1, 128><<<dim3(8, 64, 1), 256, 0, stream>>>(
      hs_bf, W1, b1c, t1, HIDDEN, HIDDEN, 1024, HIDDEN, 0, 0, 0);

  // GEMM2: z=0 headW = t1[:,:512] @ MT^T ; z=1 dep = t1[:,512:] @ W2^T
  k_gemm_bt<false, true, 0, 128><<<dim3(4, 64, 2), 256, 0, stream>>>(
      t1, MT, nullptr, hw, 1024, AP, AP, AP,
      /*aBS=*/AP, /*bBS=*/(long)AP * AP, /*cBS=*/(long)ROWS * AP);

  // GEMM3: scores[b] = headW_b @ dep_b^T + bb  -> f32 out, 16 batches, BN=64
  k_gemm_bt<false, false, 2, 64><<<dim3(8, 4, 16), 256, 0, stream>>>(
      hw, hw + (size_t)ROWS * AP, bb, out, AP, AP, 512, AP,
      /*aBS=*/(long)512 * AP, /*bBS=*/(long)512 * AP, /*cBS=*/(long)512 * 512);
}

// Round 4
// 173.062 us; speedup vs baseline: 1.2023x; 1.0248x over previous
//
#include <hip/hip_runtime.h>
#include <hip/hip_bf16.h>

// BiaffineAttention on MI355X — round 3 (resubmit; r3 bench was an infra
// timeout, kernel never ran).
// bf16 MFMA GEMMs with 2-phase double-buffered pipeline (T3 minimum recipe):
//   stage(next tile) issued BEFORE compute(cur); ONE barrier per K-step.
// Launches (4): k_prep_all (weights+conv), k_g1mt (GEMM1 + MT rides along),
//               k_g2 (headW|dep, z=2), k_g3 (scores, z=16 -> f32 out).
// Algebraic folds (verified r2, absmax 0.031):
//   MT = WbT @ w2hT^T with w2hT row 511 = b2h  -> headW bias folded
//   W2 col 511 = b2d; b1c[511]=b1c[1023]=1 -> t1[:,511]=t1[:,1023]=1
//   GEMM2 biasless; GEMM3 adds scalar bb[0].

#define HIDDEN 1024
#define ARC 500
#define AP 512
#define ROWS 8192

typedef __attribute__((ext_vector_type(4))) float f32x4;
typedef __attribute__((ext_vector_type(8))) short short8;

static __device__ __forceinline__ ushort f2bf(float f) {
  union { float f; unsigned u; } v; v.f = f;
  unsigned r = v.u + 0x7fffu + ((v.u >> 16) & 1u);  // RNE
  return (ushort)(r >> 16);
}

// Fused weight-prep + hs fp32->bf16 conversion. Block ranges:
//  [0,4096)    W1 [1024x1024]: rows 0..499=w1h, 512..1011=w1d, else 0
//  [4096,5120) WbT[a][j] = Wb[j][a]
//  [5120,6144) w2hT[k][j] = w2h[j][k]; row 511 = b2h
//  [6144,7168) W2 = w2d padded; col 511 = b2d
//  [7168,7172) b1c: b1h | 0 | 1 | b1d | 0 | 1
//  [7172,9220) hs fp32 -> bf16 (grid-stride float4)
__global__ void k_prep_all(const float* __restrict__ w1h, const float* __restrict__ b1h,
                           const float* __restrict__ w1d, const float* __restrict__ b1d,
                           const float* __restrict__ w2h, const float* __restrict__ b2h,
                           const float* __restrict__ w2d, const float* __restrict__ b2d,
                           const float* __restrict__ Wb, const float4* __restrict__ hs,
                           ushort* __restrict__ W1, ushort* __restrict__ WbT,
                           ushort* __restrict__ w2hT, ushort* __restrict__ W2,
                           float* __restrict__ b1c, ushort* __restrict__ hs_bf) {
  const int bid = blockIdx.x;
  const int tid = threadIdx.x;
  if (bid < 4096) {
    int idx = bid * 256 + tid;
    int n = idx >> 10, k = idx & 1023;
    float v = 0.f;
    if (n < ARC) v = w1h[(size_t)n * HIDDEN + k];
    else if (n >= AP && n < AP + ARC) v = w1d[(size_t)(n - AP) * HIDDEN + k];
    W1[idx] = f2bf(v);
  } else if (bid < 5120) {
    int idx = (bid - 4096) * 256 + tid;
    int a = idx >> 9, j = idx & 511;
    float v = (a < ARC && j < ARC) ? Wb[(size_t)j * ARC + a] : 0.f;
    WbT[idx] = f2bf(v);
  } else if (bid < 6144) {
    int idx = (bid - 5120) * 256 + tid;
    int k = idx >> 9, j = idx & 511;
    float v = 0.f;
    if (j < ARC) {
      if (k < ARC) v = w2h[(size_t)j * ARC + k];
      else if (k == 511) v = b2h[j];
    }
    w2hT[idx] = f2bf(v);
  } else if (bid < 7168) {
    int idx = (bid - 6144) * 256 + tid;
    int n = idx >> 9, k = idx & 511;
    float v = 0.f;
    if (n < ARC) {
      if (k < ARC) v = w2d[(size_t)n * ARC + k];
      else if (k == 511) v = b2d[n];
    }
    W2[idx] = f2bf(v);
  } else if (bid < 7172) {
    int i = (bid - 7168) * 256 + tid;
    float v = 0.f;
    if (i < ARC) v = b1h[i];
    else if (i == 511 || i == 1023) v = 1.f;
    else if (i >= AP && i < AP + ARC) v = b1d[i - AP];
    b1c[i] = v;
  } else {
    const int n4 = ROWS * HIDDEN / 4;
    int i = (bid - 7172) * 256 + tid;
    for (; i < n4; i += 2048 * 256) {
      float4 v = hs[i];
      ushort4 o;
      o.x = f2bf(v.x); o.y = f2bf(v.y); o.z = f2bf(v.z); o.w = f2bf(v.w);
      *(ushort4*)(hs_bf + (size_t)i * 4) = o;
    }
  }
}

// ---- 2-phase double-buffered bf16 GEMM body: C = A @ B^T -------------------
// 128xBN tile, BK=32, 256 threads (4 waves 2x2), 16x16x32 bf16 MFMA.
// LDS carve (ushorts): As0[4096] As1[4096] Bs0[BN*32] Bs1[BN*32].
// Pipeline: stage(t+1) issued before compute(t); ONE __syncthreads per K-step
// (its implicit vmcnt(0)+lgkmcnt(0) drain publishes the prefetched buffer and
// protects the buffer being overwritten). nt = K/32 must be even (K=512/1024).
template <int BN>
__device__ __forceinline__ void gemm_body(
    const ushort* __restrict__ A, const ushort* __restrict__ B,
    const float* __restrict__ bias, int bias_mode,  // 0 none, 1 per-col, 2 scalar
    void* __restrict__ C, int out_bf16, int relu,
    int lda, int ldb, int ldc, int K, int tm, int tn, ushort* lds) {
  constexpr int WC = BN / 2;
  constexpr int NFR = WC / 16;
  ushort* As0 = lds;
  ushort* As1 = lds + 4096;
  ushort* Bs0 = lds + 8192;
  ushort* Bs1 = lds + 8192 + BN * 32;

  const int t = threadIdx.x;
  const int w = t >> 6;
  const int l = t & 63;
  const int wr = w >> 1, wc = w & 1;

  f32x4 acc[4][NFR];
#pragma unroll
  for (int m = 0; m < 4; ++m)
#pragma unroll
    for (int n = 0; n < NFR; ++n) acc[m][n] = f32x4{0.f, 0.f, 0.f, 0.f};

  const int srow = w * 16 + (l >> 2);
  const int scol = (l & 3) * 8;
  const ushort* ag = A + (size_t)(tm + srow) * lda + scol;
  const ushort* bg = B + (size_t)(tn + srow) * ldb + scol;
  const int lofs = w * 512;  // wave-uniform LDS staging base (ushorts)

  const int fr = l & 15, fh = l >> 4;
  const int fAo = (wr * 64 + fr) * 32 + fh * 8;
  const int fBo = (wc * WC + fr) * 32 + fh * 8;

  auto stage = [&](int kt, ushort* lA, ushort* lB) {
#pragma unroll
    for (int c = 0; c < 2; ++c)
      __builtin_amdgcn_global_load_lds(
          (const __attribute__((address_space(1))) void*)(ag + (size_t)c * 64 * lda + kt),
          (__attribute__((address_space(3))) void*)(lA + lofs + c * 2048), 16, 0, 0);
#pragma unroll
    for (int c = 0; c < BN / 64; ++c)
      __builtin_amdgcn_global_load_lds(
          (const __attribute__((address_space(1))) void*)(bg + (size_t)c * 64 * ldb + kt),
          (__attribute__((address_space(3))) void*)(lB + lofs + c * 2048), 16, 0, 0);
  };
  auto compute = [&](const ushort* As, const ushort* Bs) {
    short8 af[4], bf[NFR];
#pragma unroll
    for (int m = 0; m < 4; ++m) af[m] = *(const short8*)(As + fAo + m * 16 * 32);
#pragma unroll
    for (int n = 0; n < NFR; ++n) bf[n] = *(const short8*)(Bs + fBo + n * 16 * 32);
#pragma unroll
    for (int m = 0; m < 4; ++m)
#pragma unroll
      for (int n = 0; n < NFR; ++n)
        acc[m][n] = __builtin_amdgcn_mfma_f32_16x16x32_bf16(af[m], bf[n], acc[m][n], 0, 0, 0);
  };

  const int nt = K >> 5;
  stage(0, As0, Bs0);
  for (int ti = 0; ti < nt; ti += 2) {
    __syncthreads();                                  // publishes buf0 of step ti
    if (ti + 1 < nt) stage((ti + 1) << 5, As1, Bs1);  // prefetch next
    compute(As0, Bs0);
    __syncthreads();                                  // publishes buf1
    if (ti + 2 < nt) stage((ti + 2) << 5, As0, Bs0);
    compute(As1, Bs1);
  }

  // C/D layout: col = lane&15, row = (lane>>4)*4 + j  [m89-verified]
  const int cr = fh * 4;
  const float bscal = (bias_mode == 2) ? bias[0] : 0.f;
#pragma unroll
  for (int m = 0; m < 4; ++m) {
#pragma unroll
    for (int n = 0; n < NFR; ++n) {
      const int col = tn + wc * WC + n * 16 + fr;
      const float bv = (bias_mode == 1) ? bias[col] : bscal;
#pragma unroll
      for (int j = 0; j < 4; ++j) {
        const int row = tm + wr * 64 + m * 16 + cr + j;
        float v = acc[m][n][j] + bv;
        if (relu) v = fmaxf(v, 0.f);
        if (out_bf16)
          ((ushort*)C)[(size_t)row * ldc + col] = f2bf(v);
        else
          ((float*)C)[(size_t)row * ldc + col] = v;
      }
    }
  }
}

// GEMM1 (t1 = relu(hs@W1^T + b1c), 8192x1024 K=1024) + MT GEMM rides along.
// grid (8, 66): by<64 -> GEMM1 tile; by>=64 -> MT = WbT @ w2hT^T [512x512] K=512.
__global__ __launch_bounds__(256)
void k_g1mt(const ushort* __restrict__ hs_bf, const ushort* __restrict__ W1,
            const float* __restrict__ b1c, ushort* __restrict__ t1,
            const ushort* __restrict__ WbT, const ushort* __restrict__ w2hT,
            ushort* __restrict__ MTb) {
  __shared__ ushort lds[16384];
  const int flat = blockIdx.y * 8 + blockIdx.x;  // 528 blocks, %8==0
  const int f2 = (flat & 7) * 66 + (flat >> 3);  // XCD-bijective swizzle
  const int by = f2 >> 3, bx = f2 & 7;
  if (by < 64) {
    gemm_body<128>(hs_bf, W1, b1c, 1, t1, 1, 1,
                   HIDDEN, HIDDEN, 1024, HIDDEN, by * 128, bx * 128, lds);
  } else {
    const int idx = (by - 64) * 8 + bx;  // [0,16)
    gemm_body<128>(WbT, w2hT, nullptr, 0, MTb, 1, 0,
                   AP, AP, AP, AP, (idx >> 2) * 128, (idx & 3) * 128, lds);
  }
}

// Generic batched GEMM: z-strided A/B/C (element strides), runtime flags.
template <int BN>
__global__ __launch_bounds__(256)
void k_gemm_rt(const ushort* __restrict__ A, const ushort* __restrict__ B,
               const float* __restrict__ bias, int bias_mode,
               void* __restrict__ C, int out_bf16, int relu,
               int lda, int ldb, int ldc, int K,
               long aBS, long bBS, long cBS) {
  __shared__ ushort lds[8192 + BN * 64];
  const int gx = gridDim.x, gy = gridDim.y;
  const int gxy = gx * gy;
  const int nwg = gxy * gridDim.z;
  const int flat = (blockIdx.z * gy + blockIdx.y) * gx + blockIdx.x;
  const int q = nwg >> 3;
  const int f2 = (flat & 7) * q + (flat >> 3);  // bijective: nwg % 8 == 0
  const int bz = f2 / gxy;
  const int rm = f2 - bz * gxy;
  const int by = rm / gx;
  const int bx = rm - by * gx;

  const ushort* Az = A + (size_t)aBS * bz;
  const ushort* Bz = B + (size_t)bBS * bz;
  void* Cz = out_bf16 ? (void*)((ushort*)C + (size_t)cBS * bz)
                      : (void*)((float*)C + (size_t)cBS * bz);
  gemm_body<BN>(Az, Bz, bias, bias_mode, Cz, out_bf16, relu,
                lda, ldb, ldc, K, by * 128, bx * BN, lds);
}

extern "C" void kernel_launch(void* const* d_in, const int* in_sizes, int n_in,
                              void* d_out, int out_size, void* d_ws, size_t ws_size,
                              hipStream_t stream) {
  const float* hs  = (const float*)d_in[0];
  const float* w1h = (const float*)d_in[1];
  const float* b1h = (const float*)d_in[2];
  const float* w2h = (const float*)d_in[3];
  const float* b2h = (const float*)d_in[4];
  const float* w1d = (const float*)d_in[5];
  const float* b1d = (const float*)d_in[6];
  const float* w2d = (const float*)d_in[7];
  const float* b2d = (const float*)d_in[8];
  const float* Wb  = (const float*)d_in[9];
  const float* bb  = (const float*)d_in[10];

  char* ws = (char*)d_ws;
  ushort* hs_bf = (ushort*)(ws + 0);          // 16 MB
  ushort* W1    = (ushort*)(ws + 16777216);   // 2 MB
  ushort* WbT   = (ushort*)(ws + 18874368);   // 512 KB
  ushort* w2hT  = (ushort*)(ws + 19398656);   // 512 KB
  ushort* MT    = (ushort*)(ws + 19922944);   // 512 KB
  ushort* W2    = (ushort*)(ws + 20447232);   // 512 KB (= MT + 512*512 elems!)
  ushort* t1    = (ushort*)(ws + 20971520);   // 16 MB
  ushort* hw    = (ushort*)(ws + 37748736);   // 16 MB (headW 8MB | dep 8MB)
  float*  b1c   = (float*)(ws + 54525952);    // 4 KB
  float*  out   = (float*)d_out;

  k_prep_all<<<9220, 256, 0, stream>>>(w1h, b1h, w1d, b1d, w2h, b2h, w2d, b2d,
                                       Wb, (const float4*)hs,
                                       W1, WbT, w2hT, W2, b1c, hs_bf);

  // GEMM1 + MT in one dispatch
  k_g1mt<<<dim3(8, 66), 256, 0, stream>>>(hs_bf, W1, b1c, t1, WbT, w2hT, MT);

  // GEMM2: z=0 headW = t1[:,:512] @ MT^T ; z=1 dep = t1[:,512:] @ W2^T
  k_gemm_rt<128><<<dim3(4, 64, 2), 256, 0, stream>>>(
      t1, MT, nullptr, 0, hw, 1, 0, 1024, AP, AP, AP,
      /*aBS=*/AP, /*bBS=*/(long)AP * AP, /*cBS=*/(long)ROWS * AP);

  // GEMM3: scores[b] = headW_b @ dep_b^T + bb -> f32 out, 16 batches, BN=64
  k_gemm_rt<64><<<dim3(8, 4, 16), 256, 0, stream>>>(
      hw, hw + (size_t)ROWS * AP, bb, 2, out, 0, 0, AP, AP, 512, AP,
      /*aBS=*/(long)512 * AP, /*bBS=*/(long)512 * AP, /*cBS=*/(long)512 * 512);
}

// Round 6
// 171.826 us; speedup vs baseline: 1.2110x; 1.0072x over previous
//
#include <hip/hip_runtime.h>
#include <hip/hip_bf16.h>

// BiaffineAttention on MI355X — round 5 (resubmit; r5 bench was an infra
// timeout, kernel never ran).
// r4 -> r5: LDS XOR-swizzle (T2, rule-21 both-sides) on the GEMM fragment path.
//   BK=32 bf16 rows are 64B; un-swizzled ds_read_b128 fragments were an 8-way
//   bank conflict (2.13M SQ_LDS_BANK_CONFLICT on k_g1mt, MfmaUtil 15%).
//   chunk ^= (row>>1)&3 applied as: pre-swizzled GLOBAL source address in the
//   global_load_lds staging (LDS stays linear-write) + swizzled ds_read offset.
// Structure otherwise identical to r4 (2-phase dbuf, 4 launches).

#define HIDDEN 1024
#define ARC 500
#define AP 512
#define ROWS 8192

typedef __attribute__((ext_vector_type(4))) float f32x4;
typedef __attribute__((ext_vector_type(8))) short short8;

static __device__ __forceinline__ ushort f2bf(float f) {
  union { float f; unsigned u; } v; v.f = f;
  unsigned r = v.u + 0x7fffu + ((v.u >> 16) & 1u);  // RNE
  return (ushort)(r >> 16);
}

// Fused weight-prep + hs fp32->bf16 conversion. Block ranges:
//  [0,4096)    W1 [1024x1024]: rows 0..499=w1h, 512..1011=w1d, else 0
//  [4096,5120) WbT[a][j] = Wb[j][a]
//  [5120,6144) w2hT[k][j] = w2h[j][k]; row 511 = b2h
//  [6144,7168) W2 = w2d padded; col 511 = b2d
//  [7168,7172) b1c: b1h | 0 | 1 | b1d | 0 | 1
//  [7172,9220) hs fp32 -> bf16 (grid-stride float4)
__global__ void k_prep_all(const float* __restrict__ w1h, const float* __restrict__ b1h,
                           const float* __restrict__ w1d, const float* __restrict__ b1d,
                           const float* __restrict__ w2h, const float* __restrict__ b2h,
                           const float* __restrict__ w2d, const float* __restrict__ b2d,
                           const float* __restrict__ Wb, const float4* __restrict__ hs,
                           ushort* __restrict__ W1, ushort* __restrict__ WbT,
                           ushort* __restrict__ w2hT, ushort* __restrict__ W2,
                           float* __restrict__ b1c, ushort* __restrict__ hs_bf) {
  const int bid = blockIdx.x;
  const int tid = threadIdx.x;
  if (bid < 4096) {
    int idx = bid * 256 + tid;
    int n = idx >> 10, k = idx & 1023;
    float v = 0.f;
    if (n < ARC) v = w1h[(size_t)n * HIDDEN + k];
    else if (n >= AP && n < AP + ARC) v = w1d[(size_t)(n - AP) * HIDDEN + k];
    W1[idx] = f2bf(v);
  } else if (bid < 5120) {
    int idx = (bid - 4096) * 256 + tid;
    int a = idx >> 9, j = idx & 511;
    float v = (a < ARC && j < ARC) ? Wb[(size_t)j * ARC + a] : 0.f;
    WbT[idx] = f2bf(v);
  } else if (bid < 6144) {
    int idx = (bid - 5120) * 256 + tid;
    int k = idx >> 9, j = idx & 511;
    float v = 0.f;
    if (j < ARC) {
      if (k < ARC) v = w2h[(size_t)j * ARC + k];
      else if (k == 511) v = b2h[j];
    }
    w2hT[idx] = f2bf(v);
  } else if (bid < 7168) {
    int idx = (bid - 6144) * 256 + tid;
    int n = idx >> 9, k = idx & 511;
    float v = 0.f;
    if (n < ARC) {
      if (k < ARC) v = w2d[(size_t)n * ARC + k];
      else if (k == 511) v = b2d[n];
    }
    W2[idx] = f2bf(v);
  } else if (bid < 7172) {
    int i = (bid - 7168) * 256 + tid;
    float v = 0.f;
    if (i < ARC) v = b1h[i];
    else if (i == 511 || i == 1023) v = 1.f;
    else if (i >= AP && i < AP + ARC) v = b1d[i - AP];
    b1c[i] = v;
  } else {
    const int n4 = ROWS * HIDDEN / 4;
    int i = (bid - 7172) * 256 + tid;
    for (; i < n4; i += 2048 * 256) {
      float4 v = hs[i];
      ushort4 o;
      o.x = f2bf(v.x); o.y = f2bf(v.y); o.z = f2bf(v.z); o.w = f2bf(v.w);
      *(ushort4*)(hs_bf + (size_t)i * 4) = o;
    }
  }
}

// ---- 2-phase double-buffered bf16 GEMM body: C = A @ B^T -------------------
// 128xBN tile, BK=32, 256 threads (4 waves 2x2), 16x16x32 bf16 MFMA.
// LDS swizzle: physical 16B-chunk p at row r holds global chunk p ^ ((r>>1)&3).
//   stage: linear LDS write, per-lane pre-swizzled global source chunk
//          (l&3) ^ ((l>>3)&3)   [srow = w*16 + (l>>2), (srow>>1)&3 == (l>>3)&3]
//   read : chunk = fh ^ ((fr>>1)&3)  -> full wave reads 64 distinct 16B slots
//          (one contiguous 1KB stripe) = conflict-free.
template <int BN>
__device__ __forceinline__ void gemm_body(
    const ushort* __restrict__ A, const ushort* __restrict__ B,
    const float* __restrict__ bias, int bias_mode,  // 0 none, 1 per-col, 2 scalar
    void* __restrict__ C, int out_bf16, int relu,
    int lda, int ldb, int ldc, int K, int tm, int tn, ushort* lds) {
  constexpr int WC = BN / 2;
  constexpr int NFR = WC / 16;
  ushort* As0 = lds;
  ushort* As1 = lds + 4096;
  ushort* Bs0 = lds + 8192;
  ushort* Bs1 = lds + 8192 + BN * 32;

  const int t = threadIdx.x;
  const int w = t >> 6;
  const int l = t & 63;
  const int wr = w >> 1, wc = w & 1;

  f32x4 acc[4][NFR];
#pragma unroll
  for (int m = 0; m < 4; ++m)
#pragma unroll
    for (int n = 0; n < NFR; ++n) acc[m][n] = f32x4{0.f, 0.f, 0.f, 0.f};

  const int srow = w * 16 + (l >> 2);
  const int scol = (((l & 3) ^ ((l >> 3) & 3))) * 8;  // pre-swizzled global chunk
  const ushort* ag = A + (size_t)(tm + srow) * lda + scol;
  const ushort* bg = B + (size_t)(tn + srow) * ldb + scol;
  const int lofs = w * 512;  // wave-uniform LDS staging base (ushorts)

  const int fr = l & 15, fh = l >> 4;
  const int swz = (fr >> 1) & 3;                       // row-derived chunk XOR
  const int fAo = (wr * 64 + fr) * 32 + (fh ^ swz) * 8;
  const int fBo = (wc * WC + fr) * 32 + (fh ^ swz) * 8;

  auto stage = [&](int kt, ushort* lA, ushort* lB) {
#pragma unroll
    for (int c = 0; c < 2; ++c)
      __builtin_amdgcn_global_load_lds(
          (const __attribute__((address_space(1))) void*)(ag + (size_t)c * 64 * lda + kt),
          (__attribute__((address_space(3))) void*)(lA + lofs + c * 2048), 16, 0, 0);
#pragma unroll
    for (int c = 0; c < BN / 64; ++c)
      __builtin_amdgcn_global_load_lds(
          (const __attribute__((address_space(1))) void*)(bg + (size_t)c * 64 * ldb + kt),
          (__attribute__((address_space(3))) void*)(lB + lofs + c * 2048), 16, 0, 0);
  };
  auto compute = [&](const ushort* As, const ushort* Bs) {
    short8 af[4], bf[NFR];
#pragma unroll
    for (int m = 0; m < 4; ++m) af[m] = *(const short8*)(As + fAo + m * 16 * 32);
#pragma unroll
    for (int n = 0; n < NFR; ++n) bf[n] = *(const short8*)(Bs + fBo + n * 16 * 32);
#pragma unroll
    for (int m = 0; m < 4; ++m)
#pragma unroll
      for (int n = 0; n < NFR; ++n)
        acc[m][n] = __builtin_amdgcn_mfma_f32_16x16x32_bf16(af[m], bf[n], acc[m][n], 0, 0, 0);
  };

  const int nt = K >> 5;
  stage(0, As0, Bs0);
  for (int ti = 0; ti < nt; ti += 2) {
    __syncthreads();                                  // publishes buf0 of step ti
    if (ti + 1 < nt) stage((ti + 1) << 5, As1, Bs1);  // prefetch next
    compute(As0, Bs0);
    __syncthreads();                                  // publishes buf1
    if (ti + 2 < nt) stage((ti + 2) << 5, As0, Bs0);
    compute(As1, Bs1);
  }

  // C/D layout: col = lane&15, row = (lane>>4)*4 + j  [m89-verified]
  const int cr = fh * 4;
  const float bscal = (bias_mode == 2) ? bias[0] : 0.f;
#pragma unroll
  for (int m = 0; m < 4; ++m) {
#pragma unroll
    for (int n = 0; n < NFR; ++n) {
      const int col = tn + wc * WC + n * 16 + fr;
      const float bv = (bias_mode == 1) ? bias[col] : bscal;
#pragma unroll
      for (int j = 0; j < 4; ++j) {
        const int row = tm + wr * 64 + m * 16 + cr + j;
        float v = acc[m][n][j] + bv;
        if (relu) v = fmaxf(v, 0.f);
        if (out_bf16)
          ((ushort*)C)[(size_t)row * ldc + col] = f2bf(v);
        else
          ((float*)C)[(size_t)row * ldc + col] = v;
      }
    }
  }
}

// GEMM1 (t1 = relu(hs@W1^T + b1c), 8192x1024 K=1024) + MT GEMM rides along.
// grid (8, 66): by<64 -> GEMM1 tile; by>=64 -> MT = WbT @ w2hT^T [512x512] K=512.
__global__ __launch_bounds__(256)
void k_g1mt(const ushort* __restrict__ hs_bf, const ushort* __restrict__ W1,
            const float* __restrict__ b1c, ushort* __restrict__ t1,
            const ushort* __restrict__ WbT, const ushort* __restrict__ w2hT,
            ushort* __restrict__ MTb) {
  __shared__ ushort lds[16384];
  const int flat = blockIdx.y * 8 + blockIdx.x;  // 528 blocks, %8==0
  const int f2 = (flat & 7) * 66 + (flat >> 3);  // XCD-bijective swizzle
  const int by = f2 >> 3, bx = f2 & 7;
  if (by < 64) {
    gemm_body<128>(hs_bf, W1, b1c, 1, t1, 1, 1,
                   HIDDEN, HIDDEN, 1024, HIDDEN, by * 128, bx * 128, lds);
  } else {
    const int idx = (by - 64) * 8 + bx;  // [0,16)
    gemm_body<128>(WbT, w2hT, nullptr, 0, MTb, 1, 0,
                   AP, AP, AP, AP, (idx >> 2) * 128, (idx & 3) * 128, lds);
  }
}

// Generic batched GEMM: z-strided A/B/C (element strides), runtime flags.
template <int BN>
__global__ __launch_bounds__(256)
void k_gemm_rt(const ushort* __restrict__ A, const ushort* __restrict__ B,
               const float* __restrict__ bias, int bias_mode,
               void* __restrict__ C, int out_bf16, int relu,
               int lda, int ldb, int ldc, int K,
               long aBS, long bBS, long cBS) {
  __shared__ ushort lds[8192 + BN * 64];
  const int gx = gridDim.x, gy = gridDim.y;
  const int gxy = gx * gy;
  const int nwg = gxy * gridDim.z;
  const int flat = (blockIdx.z * gy + blockIdx.y) * gx + blockIdx.x;
  const int q = nwg >> 3;
  const int f2 = (flat & 7) * q + (flat >> 3);  // bijective: nwg % 8 == 0
  const int bz = f2 / gxy;
  const int rm = f2 - bz * gxy;
  const int by = rm / gx;
  const int bx = rm - by * gx;

  const ushort* Az = A + (size_t)aBS * bz;
  const ushort* Bz = B + (size_t)bBS * bz;
  void* Cz = out_bf16 ? (void*)((ushort*)C + (size_t)cBS * bz)
                      : (void*)((float*)C + (size_t)cBS * bz);
  gemm_body<BN>(Az, Bz, bias, bias_mode, Cz, out_bf16, relu,
                lda, ldb, ldc, K, by * 128, bx * BN, lds);
}

extern "C" void kernel_launch(void* const* d_in, const int* in_sizes, int n_in,
                              void* d_out, int out_size, void* d_ws, size_t ws_size,
                              hipStream_t stream) {
  const float* hs  = (const float*)d_in[0];
  const float* w1h = (const float*)d_in[1];
  const float* b1h = (const float*)d_in[2];
  const float* w2h = (const float*)d_in[3];
  const float* b2h = (const float*)d_in[4];
  const float* w1d = (const float*)d_in[5];
  const float* b1d = (const float*)d_in[6];
  const float* w2d = (const float*)d_in[7];
  const float* b2d = (const float*)d_in[8];
  const float* Wb  = (const float*)d_in[9];
  const float* bb  = (const float*)d_in[10];

  char* ws = (char*)d_ws;
  ushort* hs_bf = (ushort*)(ws + 0);          // 16 MB
  ushort* W1    = (ushort*)(ws + 16777216);   // 2 MB
  ushort* WbT   = (ushort*)(ws + 18874368);   // 512 KB
  ushort* w2hT  = (ushort*)(ws + 19398656);   // 512 KB
  ushort* MT    = (ushort*)(ws + 19922944);   // 512 KB
  ushort* W2    = (ushort*)(ws + 20447232);   // 512 KB (= MT + 512*512 elems!)
  ushort* t1    = (ushort*)(ws + 20971520);   // 16 MB
  ushort* hw    = (ushort*)(ws + 37748736);   // 16 MB (headW 8MB | dep 8MB)
  float*  b1c   = (float*)(ws + 54525952);    // 4 KB
  float*  out   = (float*)d_out;

  k_prep_all<<<9220, 256, 0, stream>>>(w1h, b1h, w1d, b1d, w2h, b2h, w2d, b2d,
                                       Wb, (const float4*)hs,
                                       W1, WbT, w2hT, W2, b1c, hs_bf);

  // GEMM1 + MT in one dispatch
  k_g1mt<<<dim3(8, 66), 256, 0, stream>>>(hs_bf, W1, b1c, t1, WbT, w2hT, MT);

  // GEMM2: z=0 headW = t1[:,:512] @ MT^T ; z=1 dep = t1[:,512:] @ W2^T
  k_gemm_rt<128><<<dim3(4, 64, 2), 256, 0, stream>>>(
      t1, MT, nullptr, 0, hw, 1, 0, 1024, AP, AP, AP,
      /*aBS=*/AP, /*bBS=*/(long)AP * AP, /*cBS=*/(long)ROWS * AP);

  // GEMM3: scores[b] = headW_b @ dep_b^T + bb -> f32 out, 16 batches, BN=64
  k_gemm_rt<64><<<dim3(8, 4, 16), 256, 0, stream>>>(
      hw, hw + (size_t)ROWS * AP, bb, 2, out, 0, 0, AP, AP, 512, AP,
      /*aBS=*/(long)512 * AP, /*bBS=*/(long)512 * AP, /*cBS=*/(long)512 * 512);
}

// Round 9
// 163.330 us; speedup vs baseline: 1.2740x; 1.0520x over previous
//
#include <hip/hip_runtime.h>
#include <hip/hip_bf16.h>

// BiaffineAttention on MI355X — round 8 (resubmit; r8 bench was an infra
// failure, kernel never ran).
// r7 -> r8: FIX cross-wave race in counted-vmcnt pipeline.
//   vmcnt is PER-WAVE; the tile is staged cooperatively by 4 waves. The wait
//   must come BEFORE the barrier (each wave certifies its own loads landed,
//   barrier then certifies all waves'). r7 had barrier-then-wait -> wave A
//   read LDS rows whose loads (issued by wave B) were still in flight.
// Per K-step now:  vmcnt(LPS) [vmcnt(0) last iter]; s_barrier; stage(t+2);
//                  compute(t).  3 LDS slots, 2-deep prefetch.
// Keeps: T2 both-sides LDS XOR-swizzle (r6: conflicts 2.13M->0),
//        XCD-bijective block swizzle, algebraic bias folds, 4 launches.

#define HIDDEN 1024
#define ARC 500
#define AP 512
#define ROWS 8192

typedef __attribute__((ext_vector_type(4))) float f32x4;
typedef __attribute__((ext_vector_type(8))) short short8;

static __device__ __forceinline__ ushort f2bf(float f) {
  union { float f; unsigned u; } v; v.f = f;
  unsigned r = v.u + 0x7fffu + ((v.u >> 16) & 1u);  // RNE
  return (ushort)(r >> 16);
}

// Fused weight-prep + hs fp32->bf16 conversion. Block ranges:
//  [0,4096)    W1 [1024x1024]: rows 0..499=w1h, 512..1011=w1d, else 0
//  [4096,5120) WbT[a][j] = Wb[j][a]
//  [5120,6144) w2hT[k][j] = w2h[j][k]; row 511 = b2h
//  [6144,7168) W2 = w2d padded; col 511 = b2d
//  [7168,7172) b1c: b1h | 0 | 1 | b1d | 0 | 1
//  [7172,9220) hs fp32 -> bf16 (grid-stride float4)
__global__ void k_prep_all(const float* __restrict__ w1h, const float* __restrict__ b1h,
                           const float* __restrict__ w1d, const float* __restrict__ b1d,
                           const float* __restrict__ w2h, const float* __restrict__ b2h,
                           const float* __restrict__ w2d, const float* __restrict__ b2d,
                           const float* __restrict__ Wb, const float4* __restrict__ hs,
                           ushort* __restrict__ W1, ushort* __restrict__ WbT,
                           ushort* __restrict__ w2hT, ushort* __restrict__ W2,
                           float* __restrict__ b1c, ushort* __restrict__ hs_bf) {
  const int bid = blockIdx.x;
  const int tid = threadIdx.x;
  if (bid < 4096) {
    int idx = bid * 256 + tid;
    int n = idx >> 10, k = idx & 1023;
    float v = 0.f;
    if (n < ARC) v = w1h[(size_t)n * HIDDEN + k];
    else if (n >= AP && n < AP + ARC) v = w1d[(size_t)(n - AP) * HIDDEN + k];
    W1[idx] = f2bf(v);
  } else if (bid < 5120) {
    int idx = (bid - 4096) * 256 + tid;
    int a = idx >> 9, j = idx & 511;
    float v = (a < ARC && j < ARC) ? Wb[(size_t)j * ARC + a] : 0.f;
    WbT[idx] = f2bf(v);
  } else if (bid < 6144) {
    int idx = (bid - 5120) * 256 + tid;
    int k = idx >> 9, j = idx & 511;
    float v = 0.f;
    if (j < ARC) {
      if (k < ARC) v = w2h[(size_t)j * ARC + k];
      else if (k == 511) v = b2h[j];
    }
    w2hT[idx] = f2bf(v);
  } else if (bid < 7168) {
    int idx = (bid - 6144) * 256 + tid;
    int n = idx >> 9, k = idx & 511;
    float v = 0.f;
    if (n < ARC) {
      if (k < ARC) v = w2d[(size_t)n * ARC + k];
      else if (k == 511) v = b2d[n];
    }
    W2[idx] = f2bf(v);
  } else if (bid < 7172) {
    int i = (bid - 7168) * 256 + tid;
    float v = 0.f;
    if (i < ARC) v = b1h[i];
    else if (i == 511 || i == 1023) v = 1.f;
    else if (i >= AP && i < AP + ARC) v = b1d[i - AP];
    b1c[i] = v;
  } else {
    const int n4 = ROWS * HIDDEN / 4;
    int i = (bid - 7172) * 256 + tid;
    for (; i < n4; i += 2048 * 256) {
      float4 v = hs[i];
      ushort4 o;
      o.x = f2bf(v.x); o.y = f2bf(v.y); o.z = f2bf(v.z); o.w = f2bf(v.w);
      *(ushort4*)(hs_bf + (size_t)i * 4) = o;
    }
  }
}

// ---- counted-vmcnt triple-buffered bf16 GEMM body: C = A @ B^T -------------
// 128xBN tile, BK=32, 256 threads (4 waves 2x2), 16x16x32 bf16 MFMA.
// Buffer layout per slot (BUFSZ ushorts): A[4096] | B[BN*32]; 3 slots.
// LDS swizzle (T2, both-sides): physical 16B-chunk p at row r holds global
// chunk p ^ ((r>>1)&3); staged via pre-swizzled global source, read via
// chunk = fh ^ ((fr>>1)&3)  -> conflict-free (verified r6: conflicts = 0).
template <int BN>
__device__ __forceinline__ void gemm_body(
    const ushort* __restrict__ A, const ushort* __restrict__ B,
    const float* __restrict__ bias, int bias_mode,  // 0 none, 1 per-col, 2 scalar
    void* __restrict__ C, int out_bf16, int relu,
    int lda, int ldb, int ldc, int K, int tm, int tn, ushort* lds) {
  constexpr int WC = BN / 2;
  constexpr int NFR = WC / 16;
  constexpr int BUFSZ = 4096 + BN * 32;  // ushorts per buffer slot

  const int t = threadIdx.x;
  const int w = t >> 6;
  const int l = t & 63;
  const int wr = w >> 1, wc = w & 1;

  f32x4 acc[4][NFR];
#pragma unroll
  for (int m = 0; m < 4; ++m)
#pragma unroll
    for (int n = 0; n < NFR; ++n) acc[m][n] = f32x4{0.f, 0.f, 0.f, 0.f};

  const int srow = w * 16 + (l >> 2);
  const int scol = (((l & 3) ^ ((l >> 3) & 3))) * 8;  // pre-swizzled global chunk
  const ushort* ag = A + (size_t)(tm + srow) * lda + scol;
  const ushort* bg = B + (size_t)(tn + srow) * ldb + scol;
  const int lofs = w * 512;  // wave-uniform LDS staging base (ushorts)

  const int fr = l & 15, fh = l >> 4;
  const int swz = (fr >> 1) & 3;                       // row-derived chunk XOR
  const int fAo = (wr * 64 + fr) * 32 + (fh ^ swz) * 8;
  const int fBo = (wc * WC + fr) * 32 + (fh ^ swz) * 8;

  auto stage = [&](int kt, ushort* buf) {
#pragma unroll
    for (int c = 0; c < 2; ++c)
      __builtin_amdgcn_global_load_lds(
          (const __attribute__((address_space(1))) void*)(ag + (size_t)c * 64 * lda + kt),
          (__attribute__((address_space(3))) void*)(buf + lofs + c * 2048), 16, 0, 0);
#pragma unroll
    for (int c = 0; c < BN / 64; ++c)
      __builtin_amdgcn_global_load_lds(
          (const __attribute__((address_space(1))) void*)(bg + (size_t)c * 64 * ldb + kt),
          (__attribute__((address_space(3))) void*)(buf + 4096 + lofs + c * 2048), 16, 0, 0);
  };
  auto compute = [&](const ushort* buf) {
    short8 af[4], bf[NFR];
#pragma unroll
    for (int m = 0; m < 4; ++m) af[m] = *(const short8*)(buf + fAo + m * 16 * 32);
#pragma unroll
    for (int n = 0; n < NFR; ++n) bf[n] = *(const short8*)(buf + 4096 + fBo + n * 16 * 32);
#pragma unroll
    for (int m = 0; m < 4; ++m)
#pragma unroll
      for (int n = 0; n < NFR; ++n)
        acc[m][n] = __builtin_amdgcn_mfma_f32_16x16x32_bf16(af[m], bf[n], acc[m][n], 0, 0, 0);
  };

  const int nt = K >> 5;  // >= 16 for all our GEMMs
  stage(0, lds);
  stage(32, lds + BUFSZ);
  int cs = 0, ps = 2;
  for (int ti = 0; ti < nt; ++ti) {
    // WAIT FIRST (per-wave): my stage(ti) loads have landed in LDS.
    if (ti + 1 < nt) {
      if constexpr (BN == 128) asm volatile("s_waitcnt vmcnt(4)" ::: "memory");
      else                     asm volatile("s_waitcnt vmcnt(3)" ::: "memory");
    } else {
      asm volatile("s_waitcnt vmcnt(0)" ::: "memory");  // final: nothing newer
    }
    // THEN BARRIER: all waves certified their stage(ti) loads -> tile ready.
    // (Also: all waves done reading slot (ti-1)%3, so stage(ti+2) may reuse.)
    __builtin_amdgcn_s_barrier();
    __builtin_amdgcn_sched_barrier(0);
    if (ti + 2 < nt) stage((ti + 2) << 5, lds + ps * BUFSZ);
    compute(lds + cs * BUFSZ);
    cs = (cs == 2) ? 0 : cs + 1;
    ps = (ps == 2) ? 0 : ps + 1;
  }

  // C/D layout: col = lane&15, row = (lane>>4)*4 + j  [m89-verified]
  const int cr = fh * 4;
  const float bscal = (bias_mode == 2) ? bias[0] : 0.f;
#pragma unroll
  for (int m = 0; m < 4; ++m) {
#pragma unroll
    for (int n = 0; n < NFR; ++n) {
      const int col = tn + wc * WC + n * 16 + fr;
      const float bv = (bias_mode == 1) ? bias[col] : bscal;
#pragma unroll
      for (int j = 0; j < 4; ++j) {
        const int row = tm + wr * 64 + m * 16 + cr + j;
        float v = acc[m][n][j] + bv;
        if (relu) v = fmaxf(v, 0.f);
        if (out_bf16)
          ((ushort*)C)[(size_t)row * ldc + col] = f2bf(v);
        else
          ((float*)C)[(size_t)row * ldc + col] = v;
      }
    }
  }
}

// GEMM1 (t1 = relu(hs@W1^T + b1c), 8192x1024 K=1024) + MT GEMM rides along.
// grid (8, 66): by<64 -> GEMM1 tile; by>=64 -> MT = WbT @ w2hT^T [512x512] K=512.
__global__ __launch_bounds__(256)
void k_g1mt(const ushort* __restrict__ hs_bf, const ushort* __restrict__ W1,
            const float* __restrict__ b1c, ushort* __restrict__ t1,
            const ushort* __restrict__ WbT, const ushort* __restrict__ w2hT,
            ushort* __restrict__ MTb) {
  __shared__ ushort lds[3 * 8192];  // 48 KB: 3 slots x (A 8KB | B 8KB)
  const int flat = blockIdx.y * 8 + blockIdx.x;  // 528 blocks, %8==0
  const int f2 = (flat & 7) * 66 + (flat >> 3);  // XCD-bijective swizzle
  const int by = f2 >> 3, bx = f2 & 7;
  if (by < 64) {
    gemm_body<128>(hs_bf, W1, b1c, 1, t1, 1, 1,
                   HIDDEN, HIDDEN, 1024, HIDDEN, by * 128, bx * 128, lds);
  } else {
    const int idx = (by - 64) * 8 + bx;  // [0,16)
    gemm_body<128>(WbT, w2hT, nullptr, 0, MTb, 1, 0,
                   AP, AP, AP, AP, (idx >> 2) * 128, (idx & 3) * 128, lds);
  }
}

// Generic batched GEMM: z-strided A/B/C (element strides), runtime flags.
template <int BN>
__global__ __launch_bounds__(256)
void k_gemm_rt(const ushort* __restrict__ A, const ushort* __restrict__ B,
               const float* __restrict__ bias, int bias_mode,
               void* __restrict__ C, int out_bf16, int relu,
               int lda, int ldb, int ldc, int K,
               long aBS, long bBS, long cBS) {
  __shared__ ushort lds[3 * (4096 + BN * 32)];
  const int gx = gridDim.x, gy = gridDim.y;
  const int gxy = gx * gy;
  const int nwg = gxy * gridDim.z;
  const int flat = (blockIdx.z * gy + blockIdx.y) * gx + blockIdx.x;
  const int q = nwg >> 3;
  const int f2 = (flat & 7) * q + (flat >> 3);  // bijective: nwg % 8 == 0
  const int bz = f2 / gxy;
  const int rm = f2 - bz * gxy;
  const int by = rm / gx;
  const int bx = rm - by * gx;

  const ushort* Az = A + (size_t)aBS * bz;
  const ushort* Bz = B + (size_t)bBS * bz;
  void* Cz = out_bf16 ? (void*)((ushort*)C + (size_t)cBS * bz)
                      : (void*)((float*)C + (size_t)cBS * bz);
  gemm_body<BN>(Az, Bz, bias, bias_mode, Cz, out_bf16, relu,
                lda, ldb, ldc, K, by * 128, bx * BN, lds);
}

extern "C" void kernel_launch(void* const* d_in, const int* in_sizes, int n_in,
                              void* d_out, int out_size, void* d_ws, size_t ws_size,
                              hipStream_t stream) {
  const float* hs  = (const float*)d_in[0];
  const float* w1h = (const float*)d_in[1];
  const float* b1h = (const float*)d_in[2];
  const float* w2h = (const float*)d_in[3];
  const float* b2h = (const float*)d_in[4];
  const float* w1d = (const float*)d_in[5];
  const float* b1d = (const float*)d_in[6];
  const float* w2d = (const float*)d_in[7];
  const float* b2d = (const float*)d_in[8];
  const float* Wb  = (const float*)d_in[9];
  const float* bb  = (const float*)d_in[10];

  char* ws = (char*)d_ws;
  ushort* hs_bf = (ushort*)(ws + 0);          // 16 MB
  ushort* W1    = (ushort*)(ws + 16777216);   // 2 MB
  ushort* WbT   = (ushort*)(ws + 18874368);   // 512 KB
  ushort* w2hT  = (ushort*)(ws + 19398656);   // 512 KB
  ushort* MT    = (ushort*)(ws + 19922944);   // 512 KB
  ushort* W2    = (ushort*)(ws + 20447232);   // 512 KB (= MT + 512*512 elems!)
  ushort* t1    = (ushort*)(ws + 20971520);   // 16 MB
  ushort* hw    = (ushort*)(ws + 37748736);   // 16 MB (headW 8MB | dep 8MB)
  float*  b1c   = (float*)(ws + 54525952);    // 4 KB
  float*  out   = (float*)d_out;

  k_prep_all<<<9220, 256, 0, stream>>>(w1h, b1h, w1d, b1d, w2h, b2h, w2d, b2d,
                                       Wb, (const float4*)hs,
                                       W1, WbT, w2hT, W2, b1c, hs_bf);

  // GEMM1 + MT in one dispatch
  k_g1mt<<<dim3(8, 66), 256, 0, stream>>>(hs_bf, W1, b1c, t1, WbT, w2hT, MT);

  // GEMM2: z=0 headW = t1[:,:512] @ MT^T ; z=1 dep = t1[:,512:] @ W2^T
  k_gemm_rt<128><<<dim3(4, 64, 2), 256, 0, stream>>>(
      t1, MT, nullptr, 0, hw, 1, 0, 1024, AP, AP, AP,
      /*aBS=*/AP, /*bBS=*/(long)AP * AP, /*cBS=*/(long)ROWS * AP);

  // GEMM3: scores[b] = headW_b @ dep_b^T + bb -> f32 out, 16 batches, BN=64
  k_gemm_rt<64><<<dim3(8, 4, 16), 256, 0, stream>>>(
      hw, hw + (size_t)ROWS * AP, bb, 2, out, 0, 0, AP, AP, 512, AP,
      /*aBS=*/(long)512 * AP, /*bBS=*/(long)512 * AP, /*cBS=*/(long)512 * 512);
}